// Round 3
// baseline (2641.176 us; speedup 1.0000x reference)
//
#include <hip/hip_runtime.h>
#include <cstdint>
#include <cstddef>

#define T_STEPS 1000
#define NS      512
#define HID     128
#define DOUT    20
#define XPAD    129   // x tile row pad
#define WPAD    129   // transposed-weight row pad

// ---------------------------------------------------------------------------
// P0: dense precompute D[row][o] = dot(x_row, Wi1[o][:]). Bit-exact 4-acc
// stride-4 fmaf chain (verified absmax=0.0 in rounds 1-2). DO NOT reorder.
// ---------------------------------------------------------------------------
extern "C" __global__ void __launch_bounds__(512, 1)
srnn_dense(const float* __restrict__ x, const float* __restrict__ Wi1,
           float* __restrict__ D, int t0, int Tc)
{
    extern __shared__ float sm[];
    float* xs = sm;                    // [128 rows][XPAD]
    float* Wl = sm + 128 * XPAD;       // Wi1 row-major [128][128]
    const int tid = threadIdx.x;
    const int w = tid >> 6, ln = tid & 63;
    const int rb = blockIdx.x * 128;

    for (int i = tid; i < HID * HID / 4; i += 512)
        ((float4*)Wl)[i] = ((const float4*)Wi1)[i];
    for (int i = tid; i < 128 * 32; i += 512) {
        int r = i >> 5, kq = i & 31;
        int cr = rb + r;
        int s = cr / Tc, trel = cr - s * Tc;
        float4 v = ((const float4*)x)[((size_t)s * T_STEPS + t0 + trel) * 32 + kq];
        float* dst = &xs[r * XPAD + 4 * kq];
        dst[0] = v.x; dst[1] = v.y; dst[2] = v.z; dst[3] = v.w;
    }
    __syncthreads();

    const float* xr0 = xs + ln * XPAD;
    const float* xr1 = xs + (64 + ln) * XPAD;
    for (int og = 0; og < 4; ++og) {
        const int o = 16 * w + 4 * og;
        float a[2][4][4];
        #pragma unroll
        for (int r = 0; r < 2; ++r)
            #pragma unroll
            for (int j = 0; j < 4; ++j)
                #pragma unroll
                for (int i = 0; i < 4; ++i) a[r][j][i] = 0.f;

        #pragma unroll 4
        for (int k = 0; k < HID; k += 4) {
            float4 wv[4];
            #pragma unroll
            for (int j = 0; j < 4; ++j)
                wv[j] = *(const float4*)&Wl[(o + j) * HID + k];
            float xa0[4], xa1[4];
            #pragma unroll
            for (int i = 0; i < 4; ++i) { xa0[i] = xr0[k + i]; xa1[i] = xr1[k + i]; }
            #pragma unroll
            for (int j = 0; j < 4; ++j) {
                a[0][j][0] = fmaf(xa0[0], wv[j].x, a[0][j][0]);
                a[0][j][1] = fmaf(xa0[1], wv[j].y, a[0][j][1]);
                a[0][j][2] = fmaf(xa0[2], wv[j].z, a[0][j][2]);
                a[0][j][3] = fmaf(xa0[3], wv[j].w, a[0][j][3]);
                a[1][j][0] = fmaf(xa1[0], wv[j].x, a[1][j][0]);
                a[1][j][1] = fmaf(xa1[1], wv[j].y, a[1][j][1]);
                a[1][j][2] = fmaf(xa1[2], wv[j].z, a[1][j][2]);
                a[1][j][3] = fmaf(xa1[3], wv[j].w, a[1][j][3]);
            }
        }
        #pragma unroll
        for (int r = 0; r < 2; ++r) {
            float4 dv;
            dv.x = (a[r][0][0] + a[r][0][1]) + (a[r][0][2] + a[r][0][3]);
            dv.y = (a[r][1][0] + a[r][1][1]) + (a[r][1][2] + a[r][1][3]);
            dv.z = (a[r][2][0] + a[r][2][1]) + (a[r][2][2] + a[r][2][3]);
            dv.w = (a[r][3][0] + a[r][3][1]) + (a[r][3][2] + a[r][3][3]);
            *(float4*)&D[(size_t)(rb + 64 * r + ln) * HID + o] = dv;
        }
    }
}

// ---------------------------------------------------------------------------
// Sparse sum helper: pops up to 4 set bits per iteration (pad index 128 ->
// zeroed LDS row, +0.0f is exact identity), issues the 8 loads together,
// then adds ASCENDING into single accumulators — bit-identical order to the
// verified round-2 chain; only load scheduling changed.
// ---------------------------------------------------------------------------
__device__ __forceinline__ void sparse4(const float* __restrict__ WT,
                                        unsigned long long mm, int base,
                                        int ln, float& rl, float& rh)
{
    while (mm) {
        int j0 = (int)__builtin_ctzll(mm) + base;      mm &= mm - 1;
        int j1 = mm ? (int)__builtin_ctzll(mm) + base : 128; mm &= mm - 1;
        int j2 = mm ? (int)__builtin_ctzll(mm) + base : 128; mm &= mm - 1;
        int j3 = mm ? (int)__builtin_ctzll(mm) + base : 128; mm &= mm - 1;
        float a0 = WT[j0 * WPAD + ln],      a1 = WT[j1 * WPAD + ln];
        float a2 = WT[j2 * WPAD + ln],      a3 = WT[j3 * WPAD + ln];
        float b0 = WT[j0 * WPAD + 64 + ln], b1 = WT[j1 * WPAD + 64 + ln];
        float b2 = WT[j2 * WPAD + 64 + ln], b3 = WT[j3 * WPAD + 64 + ln];
        rl += a0; rl += a1; rl += a2; rl += a3;
        rh += b0; rh += b1; rh += b2; rh += b3;
    }
}

// ---------------------------------------------------------------------------
// Serial recurrence (shared by layer 1 and layer 2):
//   s(t) = spike( Dn(t) + bi + s(t-1)@Wh^T + bh )
// One wave per sample, lane owns neurons {ln, 64+ln}; masks in registers via
// ballot; 8-deep global prefetch of the dense term; no barriers in t-loop.
// ---------------------------------------------------------------------------
extern "C" __global__ void __launch_bounds__(128, 1)
srnn_recur(const float* __restrict__ Dn, const float* __restrict__ Wh,
           const float* __restrict__ bi, const float* __restrict__ bh,
           ulonglong2* __restrict__ masks, ulonglong2* __restrict__ state,
           int t0, int Tc, int first)
{
    extern __shared__ float WT[];      // [129][WPAD]; row 128 = zeros (pad row)
    const int tid = threadIdx.x, w = tid >> 6, ln = tid & 63;
    const int s = 2 * blockIdx.x + w;

    for (int i = tid; i < HID * HID / 4; i += 128) {
        int o = i >> 5, jq = i & 31;
        float4 v = ((const float4*)Wh)[i];
        WT[(4 * jq + 0) * WPAD + o] = v.x; WT[(4 * jq + 1) * WPAD + o] = v.y;
        WT[(4 * jq + 2) * WPAD + o] = v.z; WT[(4 * jq + 3) * WPAD + o] = v.w;
    }
    for (int i = tid; i < WPAD; i += 128) WT[128 * WPAD + i] = 0.f;  // pad row

    const float bil = bi[ln], bih = bi[64 + ln];
    const float bhl = bh[ln], bhh = bh[64 + ln];
    unsigned long long m0 = 0ULL, m1 = 0ULL;
    if (!first) { ulonglong2 st = state[s]; m0 = st.x; m1 = st.y; }

    const float* Drow = Dn + (size_t)s * Tc * HID;
    float dl[8], dh[8];
    #pragma unroll
    for (int p = 0; p < 8; ++p) {
        int ti = p < Tc ? p : Tc - 1;
        dl[p] = Drow[ti * HID + ln];
        dh[p] = Drow[ti * HID + 64 + ln];
    }
    __syncthreads();

    for (int tt = 0; tt < Tc; tt += 8) {
        #pragma unroll
        for (int u = 0; u < 8; ++u) {
            int t = tt + u;
            if (t >= Tc) break;                       // wave-uniform
            float dense_l = dl[u], dense_h = dh[u];
            int tp = (t + 8 < Tc) ? t + 8 : Tc - 1;
            dl[u] = Drow[tp * HID + ln];
            dh[u] = Drow[tp * HID + 64 + ln];

            float rl = 0.f, rh = 0.f;
            sparse4(WT, m0, 0,  ln, rl, rh);          // ascending, bit-exact
            sparse4(WT, m1, 64, ln, rl, rh);

            float hl = ((dense_l + bil) + rl) + bhl;  // reference add order
            float hh = ((dense_h + bih) + rh) + bhh;
            m0 = __ballot(hl >= 1.0f);
            m1 = __ballot(hh >= 1.0f);
            if (ln == 0) {
                ulonglong2 mv; mv.x = m0; mv.y = m1;
                masks[(size_t)s * T_STEPS + (t0 + t)] = mv;
            }
        }
    }
    if (ln == 0) { ulonglong2 st; st.x = m0; st.y = m1; state[s] = st; }
}

// ---------------------------------------------------------------------------
// P2: parallel sparse matmul D2[s,t,:] = s1(s,t)@Wi2^T. One wave per (s,t)
// row; ascending single-accumulator bit loop (bit-identical to round 2's A
// term). Fully parallel over 512k rows -> occupancy-saturated.
// ---------------------------------------------------------------------------
extern "C" __global__ void __launch_bounds__(256, 1)
srnn_spmm(const ulonglong2* __restrict__ masks1, const float* __restrict__ Wi2,
          float* __restrict__ D2, int t0, int Tc)
{
    extern __shared__ float WI[];      // [128][WPAD] transposed Wi2
    const int tid = threadIdx.x, w = tid >> 6, ln = tid & 63;

    for (int i = tid; i < HID * HID / 4; i += 256) {
        int o = i >> 5, jq = i & 31;
        float4 v = ((const float4*)Wi2)[i];
        WI[(4 * jq + 0) * WPAD + o] = v.x; WI[(4 * jq + 1) * WPAD + o] = v.y;
        WI[(4 * jq + 2) * WPAD + o] = v.z; WI[(4 * jq + 3) * WPAD + o] = v.w;
    }
    __syncthreads();

    const int trel = blockIdx.x * 4 + w;
    const int s = blockIdx.y;
    if (trel >= Tc) return;

    ulonglong2 m = masks1[(size_t)s * T_STEPS + (t0 + trel)];
    float Al = 0.f, Ah = 0.f;
    unsigned long long mm = m.x;
    while (mm) { int j = __builtin_ctzll(mm); mm &= mm - 1;
        Al += WI[j * WPAD + ln]; Ah += WI[j * WPAD + 64 + ln]; }
    mm = m.y;
    while (mm) { int j = 64 + __builtin_ctzll(mm); mm &= mm - 1;
        Al += WI[j * WPAD + ln]; Ah += WI[j * WPAD + 64 + ln]; }

    size_t ro = ((size_t)s * Tc + trel) * HID;
    D2[ro + ln] = Al;
    D2[ro + 64 + ln] = Ah;
}

// ---------------------------------------------------------------------------
// P4a: per-step output dots d[s,t,o] = s2(s,t)@Wo^T[:,o]. Parallel over rows.
// ---------------------------------------------------------------------------
extern "C" __global__ void __launch_bounds__(256, 1)
srnn_dots(const ulonglong2* __restrict__ masks2, const float* __restrict__ Wo,
          float* __restrict__ dots)
{
    __shared__ float WOt[HID * DOUT];  // Wo^T [j][20]
    const int tid = threadIdx.x, w = tid >> 6, ln = tid & 63;

    for (int i = tid; i < DOUT * HID / 4; i += 256) {
        int o = i >> 5, jq = i & 31;
        float4 v = ((const float4*)Wo)[i];
        WOt[(4 * jq + 0) * DOUT + o] = v.x; WOt[(4 * jq + 1) * DOUT + o] = v.y;
        WOt[(4 * jq + 2) * DOUT + o] = v.z; WOt[(4 * jq + 3) * DOUT + o] = v.w;
    }
    __syncthreads();

    const int t = blockIdx.x * 4 + w;  // grid.x = 250 -> t < 1000 always
    const int s = blockIdx.y;
    const int c = ln < DOUT ? ln : 0;  // clamp inactive lanes in-bounds

    ulonglong2 q = masks2[(size_t)s * T_STEPS + t];
    float d = 0.f;
    unsigned long long mm = q.x;
    while (mm) { int j = __builtin_ctzll(mm); mm &= mm - 1; d += WOt[j * DOUT + c]; }
    mm = q.y;
    while (mm) { int j = 64 + __builtin_ctzll(mm); mm &= mm - 1; d += WOt[j * DOUT + c]; }
    if (ln < DOUT) dots[((size_t)s * T_STEPS + t) * DOUT + ln] = d;
}

// ---------------------------------------------------------------------------
// P4b: out[s,o] = (Σ_t ascending: acc += d[s,t,o]; acc += bo[o]) / T.
// Matches the reference per-step (acc + dot) + bo order exactly.
// ---------------------------------------------------------------------------
extern "C" __global__ void __launch_bounds__(256, 1)
srnn_finish(const float* __restrict__ dots, const float* __restrict__ bo,
            float* __restrict__ out)
{
    const int idx = blockIdx.x * 256 + threadIdx.x;   // 40*256 = 10240 exact
    const int s = idx / DOUT, o = idx - s * DOUT;
    const float bov = bo[o];
    const float* dp = dots + ((size_t)s * T_STEPS) * DOUT + o;
    float acc = 0.f;
    for (int t = 0; t < T_STEPS; ++t) { acc += dp[t * DOUT]; acc += bov; }
    out[idx] = acc / (float)T_STEPS;
}

// ---------------------------------------------------------------------------
extern "C" void kernel_launch(void* const* d_in, const int* in_sizes, int n_in,
                              void* d_out, int out_size, void* d_ws, size_t ws_size,
                              hipStream_t stream) {
    const float* x   = (const float*)d_in[0];
    const float* Wi1 = (const float*)d_in[1];
    const float* bi1 = (const float*)d_in[2];
    const float* Wh1 = (const float*)d_in[3];
    const float* bh1 = (const float*)d_in[4];
    const float* Wi2 = (const float*)d_in[5];
    const float* bi2 = (const float*)d_in[6];
    const float* Wh2 = (const float*)d_in[7];
    const float* bh2 = (const float*)d_in[8];
    const float* Wo  = (const float*)d_in[9];
    const float* bo  = (const float*)d_in[10];
    float* out = (float*)d_out;

    // ws: [masks1 8.19M][masks2 8.19M][state 16K][dots 41M][D chunk buffer]
    const size_t mb = (size_t)NS * T_STEPS * sizeof(ulonglong2);
    ulonglong2* masks1 = (ulonglong2*)d_ws;
    ulonglong2* masks2 = (ulonglong2*)((char*)d_ws + mb);
    ulonglong2* state  = (ulonglong2*)((char*)d_ws + 2 * mb);
    const size_t state_bytes = (size_t)2 * NS * sizeof(ulonglong2);
    float* dots = (float*)((char*)d_ws + 2 * mb + state_bytes);
    const size_t dots_bytes = (size_t)NS * T_STEPS * DOUT * sizeof(float);
    float* D = (float*)((char*)d_ws + 2 * mb + state_bytes + dots_bytes);

    const size_t base = 2 * mb + state_bytes + dots_bytes;
    size_t avail = ws_size > base ? ws_size - base : 0;
    const size_t bytes_per_t = (size_t)NS * HID * sizeof(float);  // 256 KB
    long tcmax = (long)(avail / bytes_per_t);
    static const int divs[] = {1000, 500, 250, 200, 125, 100, 50, 40, 25, 20, 10, 8, 5, 4, 2, 1};
    int Tc = 1;
    for (int i = 0; i < 16; ++i) if (divs[i] <= tcmax) { Tc = divs[i]; break; }

    const int lds0 = (128 * XPAD + HID * HID) * (int)sizeof(float);
    const int ldsR = (129 * WPAD) * (int)sizeof(float);
    const int lds2 = (HID * WPAD) * (int)sizeof(float);
    hipFuncSetAttribute((const void*)srnn_dense,
                        hipFuncAttributeMaxDynamicSharedMemorySize, lds0);
    hipFuncSetAttribute((const void*)srnn_recur,
                        hipFuncAttributeMaxDynamicSharedMemorySize, ldsR);
    hipFuncSetAttribute((const void*)srnn_spmm,
                        hipFuncAttributeMaxDynamicSharedMemorySize, lds2);

    // Phase A: layer-1 (dense GEMM chunk -> serial recurrence chunk)
    for (int t0 = 0; t0 < T_STEPS; t0 += Tc) {
        srnn_dense<<<4 * Tc, 512, lds0, stream>>>(x, Wi1, D, t0, Tc);
        srnn_recur<<<NS / 2, 128, ldsR, stream>>>(D, Wh1, bi1, bh1,
                                                  masks1, state, t0, Tc, t0 == 0);
    }
    // Phase B: layer-2 (parallel spmm chunk -> serial recurrence chunk)
    for (int t0 = 0; t0 < T_STEPS; t0 += Tc) {
        dim3 g2((Tc + 3) / 4, NS);
        srnn_spmm<<<g2, 256, lds2, stream>>>(masks1, Wi2, D, t0, Tc);
        srnn_recur<<<NS / 2, 128, ldsR, stream>>>(D, Wh2, bi2, bh2,
                                                  masks2, state + NS, t0, Tc, t0 == 0);
    }
    // Phase C: output accumulation
    dim3 g4(250, NS);
    srnn_dots<<<g4, 256, 0, stream>>>(masks2, Wo, dots);
    srnn_finish<<<40, 256, 0, stream>>>(dots, bo, out);
}

// Round 4
// 1800.232 us; speedup vs baseline: 1.4671x; 1.4671x over previous
//
#include <hip/hip_runtime.h>
#include <cstdint>
#include <cstddef>

#define T_STEPS 1000
#define NS      512
#define HID     128
#define DOUT    20
#define XPAD    129   // x tile row pad (dense kernel)
#define PSTR    130   // paired-LDS row stride in dwords (128 pairs + 2 pad)
#define SPMM_R  32    // rows per wave in spmm

// ---------------------------------------------------------------------------
// P0: dense precompute D[row][o] = dot(x_row, Wi1[o][:]). Bit-exact 4-acc
// stride-4 fmaf chain (verified absmax=0.0 rounds 1-3). DO NOT reorder.
// ---------------------------------------------------------------------------
extern "C" __global__ void __launch_bounds__(512, 1)
srnn_dense(const float* __restrict__ x, const float* __restrict__ Wi1,
           float* __restrict__ D, int t0, int Tc)
{
    extern __shared__ float sm[];
    float* xs = sm;                    // [128 rows][XPAD]
    float* Wl = sm + 128 * XPAD;       // Wi1 row-major [128][128]
    const int tid = threadIdx.x;
    const int w = tid >> 6, ln = tid & 63;
    const int rb = blockIdx.x * 128;

    for (int i = tid; i < HID * HID / 4; i += 512)
        ((float4*)Wl)[i] = ((const float4*)Wi1)[i];
    for (int i = tid; i < 128 * 32; i += 512) {
        int r = i >> 5, kq = i & 31;
        int cr = rb + r;
        int s = cr / Tc, trel = cr - s * Tc;
        float4 v = ((const float4*)x)[((size_t)s * T_STEPS + t0 + trel) * 32 + kq];
        float* dst = &xs[r * XPAD + 4 * kq];
        dst[0] = v.x; dst[1] = v.y; dst[2] = v.z; dst[3] = v.w;
    }
    __syncthreads();

    const float* xr0 = xs + ln * XPAD;
    const float* xr1 = xs + (64 + ln) * XPAD;
    for (int og = 0; og < 4; ++og) {
        const int o = 16 * w + 4 * og;
        float a[2][4][4];
        #pragma unroll
        for (int r = 0; r < 2; ++r)
            #pragma unroll
            for (int j = 0; j < 4; ++j)
                #pragma unroll
                for (int i = 0; i < 4; ++i) a[r][j][i] = 0.f;

        #pragma unroll 4
        for (int k = 0; k < HID; k += 4) {
            float4 wv[4];
            #pragma unroll
            for (int j = 0; j < 4; ++j)
                wv[j] = *(const float4*)&Wl[(o + j) * HID + k];
            float xa0[4], xa1[4];
            #pragma unroll
            for (int i = 0; i < 4; ++i) { xa0[i] = xr0[k + i]; xa1[i] = xr1[k + i]; }
            #pragma unroll
            for (int j = 0; j < 4; ++j) {
                a[0][j][0] = fmaf(xa0[0], wv[j].x, a[0][j][0]);
                a[0][j][1] = fmaf(xa0[1], wv[j].y, a[0][j][1]);
                a[0][j][2] = fmaf(xa0[2], wv[j].z, a[0][j][2]);
                a[0][j][3] = fmaf(xa0[3], wv[j].w, a[0][j][3]);
                a[1][j][0] = fmaf(xa1[0], wv[j].x, a[1][j][0]);
                a[1][j][1] = fmaf(xa1[1], wv[j].y, a[1][j][1]);
                a[1][j][2] = fmaf(xa1[2], wv[j].z, a[1][j][2]);
                a[1][j][3] = fmaf(xa1[3], wv[j].w, a[1][j][3]);
            }
        }
        #pragma unroll
        for (int r = 0; r < 2; ++r) {
            float4 dv;
            dv.x = (a[r][0][0] + a[r][0][1]) + (a[r][0][2] + a[r][0][3]);
            dv.y = (a[r][1][0] + a[r][1][1]) + (a[r][1][2] + a[r][1][3]);
            dv.z = (a[r][2][0] + a[r][2][1]) + (a[r][2][2] + a[r][2][3]);
            dv.w = (a[r][3][0] + a[r][3][1]) + (a[r][3][2] + a[r][3][3]);
            *(float4*)&D[(size_t)(rb + 64 * r + ln) * HID + o] = dv;
        }
    }
}

// ---------------------------------------------------------------------------
// Paired-LDS staging: WT2[j*PSTR + 2*l + h] = W[h*64+l][j] (l<64, h in {0,1}),
// row 128 = zero pairs (pad). One ds_read_b64 then yields (W^T[j][l],
// W^T[j][l+64]) for lane l.
// ---------------------------------------------------------------------------
__device__ __forceinline__ void stage_paired(float* __restrict__ WT2,
                                             const float* __restrict__ W,
                                             int tid, int nthreads)
{
    for (int i = tid; i < HID * HID / 4; i += nthreads) {
        int o = i >> 5, jq = i & 31;
        float4 v = ((const float4*)W)[i];
        int c = 2 * (o & 63) + (o >> 6);
        WT2[(4 * jq + 0) * PSTR + c] = v.x;
        WT2[(4 * jq + 1) * PSTR + c] = v.y;
        WT2[(4 * jq + 2) * PSTR + c] = v.z;
        WT2[(4 * jq + 3) * PSTR + c] = v.w;
    }
    for (int i = tid; i < PSTR; i += nthreads) WT2[128 * PSTR + i] = 0.f;
}

// Sparse paired sum: pops up to 4 bits/iter (pad idx 128 -> zero pair, +0.0f
// exact identity). Adds ASCENDING: rl += a0..a3; rh += b0..b3 — bit-identical
// to the verified round-2/3 chains; only load width/scheduling changed.
__device__ __forceinline__ void sparse4p(const float* __restrict__ WT2,
                                         unsigned long long mm, int base,
                                         int ln2, float& rl, float& rh)
{
    while (mm) {
        int j0 = (int)__builtin_ctzll(mm) + base;            mm &= mm - 1;
        int j1 = mm ? (int)__builtin_ctzll(mm) + base : 128; mm &= mm - 1;
        int j2 = mm ? (int)__builtin_ctzll(mm) + base : 128; mm &= mm - 1;
        int j3 = mm ? (int)__builtin_ctzll(mm) + base : 128; mm &= mm - 1;
        float2 p0 = *(const float2*)&WT2[j0 * PSTR + ln2];
        float2 p1 = *(const float2*)&WT2[j1 * PSTR + ln2];
        float2 p2 = *(const float2*)&WT2[j2 * PSTR + ln2];
        float2 p3 = *(const float2*)&WT2[j3 * PSTR + ln2];
        rl += p0.x; rl += p1.x; rl += p2.x; rl += p3.x;
        rh += p0.y; rh += p1.y; rh += p2.y; rh += p3.y;
    }
}

// ---------------------------------------------------------------------------
// P1: layer-1 serial recurrence. One wave/sample, lane owns {ln, 64+ln};
// masks in registers (ballot); 8-deep dense-term prefetch; no barriers.
// ---------------------------------------------------------------------------
extern "C" __global__ void __launch_bounds__(128, 1)
srnn_recur1(const float* __restrict__ Dn, const float* __restrict__ Wh,
            const float* __restrict__ bi, const float* __restrict__ bh,
            ulonglong2* __restrict__ masks, ulonglong2* __restrict__ state,
            int t0, int Tc, int first)
{
    extern __shared__ float WT2[];     // [129][PSTR] paired
    const int tid = threadIdx.x, w = tid >> 6, ln = tid & 63, ln2 = 2 * ln;
    const int s = 2 * blockIdx.x + w;

    stage_paired(WT2, Wh, tid, 128);

    const float bil = bi[ln], bih = bi[64 + ln];
    const float bhl = bh[ln], bhh = bh[64 + ln];
    unsigned long long m0 = 0ULL, m1 = 0ULL;
    if (!first) { ulonglong2 st = state[s]; m0 = st.x; m1 = st.y; }

    const float* Drow = Dn + (size_t)s * Tc * HID;
    float dl[8], dh[8];
    #pragma unroll
    for (int p = 0; p < 8; ++p) {
        int ti = p < Tc ? p : Tc - 1;
        dl[p] = Drow[ti * HID + ln];
        dh[p] = Drow[ti * HID + 64 + ln];
    }
    __syncthreads();

    for (int tt = 0; tt < Tc; tt += 8) {
        #pragma unroll
        for (int u = 0; u < 8; ++u) {
            int t = tt + u;
            if (t >= Tc) break;                       // wave-uniform
            float dense_l = dl[u], dense_h = dh[u];
            int tp = (t + 8 < Tc) ? t + 8 : Tc - 1;
            dl[u] = Drow[tp * HID + ln];
            dh[u] = Drow[tp * HID + 64 + ln];

            float rl = 0.f, rh = 0.f;
            sparse4p(WT2, m0, 0,  ln2, rl, rh);       // ascending, bit-exact
            sparse4p(WT2, m1, 64, ln2, rl, rh);

            float hl = ((dense_l + bil) + rl) + bhl;  // reference add order
            float hh = ((dense_h + bih) + rh) + bhh;
            m0 = __ballot(hl >= 1.0f);
            m1 = __ballot(hh >= 1.0f);
            if (ln == 0) {
                ulonglong2 mv; mv.x = m0; mv.y = m1;
                masks[(size_t)s * T_STEPS + (t0 + t)] = mv;
            }
        }
    }
    if (ln == 0) { ulonglong2 st; st.x = m0; st.y = m1; state[s] = st; }
}

// ---------------------------------------------------------------------------
// P2: parallel sparse matmul D2[s,t,:] = s1(s,t)@Wi2^T. Each wave handles
// SPMM_R rows after ONE weight staging (round-3 staged per 4 rows: 714 us).
// Ascending single-accumulator order, bit-identical to rounds 2/3.
// ---------------------------------------------------------------------------
extern "C" __global__ void __launch_bounds__(256, 1)
srnn_spmm(const ulonglong2* __restrict__ masks1, const float* __restrict__ Wi2,
          float* __restrict__ D2, int t0, int Tc)
{
    extern __shared__ float WI2[];     // [129][PSTR] paired
    const int tid = threadIdx.x, w = tid >> 6, ln = tid & 63, ln2 = 2 * ln;
    stage_paired(WI2, Wi2, tid, 256);
    __syncthreads();

    const int s = blockIdx.y;
    const int tbase = (blockIdx.x * 4 + w) * SPMM_R;
    if (tbase >= Tc) return;
    const ulonglong2* mrow = masks1 + (size_t)s * T_STEPS + t0;

    ulonglong2 m = mrow[tbase];                       // prefetch row 0
    for (int r = 0; r < SPMM_R; ++r) {
        int trel = tbase + r;
        if (trel >= Tc) break;                        // wave-uniform
        ulonglong2 cm = m;
        if (r + 1 < SPMM_R && trel + 1 < Tc) m = mrow[trel + 1];

        float Al = 0.f, Ah = 0.f;
        sparse4p(WI2, cm.x, 0,  ln2, Al, Ah);
        sparse4p(WI2, cm.y, 64, ln2, Al, Ah);

        size_t ro = ((size_t)s * Tc + trel) * HID;
        D2[ro + ln] = Al;
        D2[ro + 64 + ln] = Ah;
    }
}

// ---------------------------------------------------------------------------
// P3: layer-2 serial recurrence WITH fused output accumulation (round-2's
// verified inline order: per step acc += dot; acc += bo). Writes out at the
// final chunk; partial acc persisted in accst across chunks.
// ---------------------------------------------------------------------------
extern "C" __global__ void __launch_bounds__(128, 1)
srnn_recur2(const float* __restrict__ D2, const float* __restrict__ Wh2,
            const float* __restrict__ bi2, const float* __restrict__ bh2,
            const float* __restrict__ Wo,  const float* __restrict__ bo,
            ulonglong2* __restrict__ state, float* __restrict__ accst,
            float* __restrict__ out, int t0, int Tc, int first, int last)
{
    extern __shared__ float sm2[];
    float* WT2 = sm2;                  // Wh2 paired [129][PSTR]
    float* WOt = sm2 + 129 * PSTR;     // Wo^T [129][DOUT], row 128 = zeros
    const int tid = threadIdx.x, w = tid >> 6, ln = tid & 63, ln2 = 2 * ln;
    const int s = 2 * blockIdx.x + w;

    stage_paired(WT2, Wh2, tid, 128);
    for (int i = tid; i < DOUT * HID / 4; i += 128) {
        int o = i >> 5, jq = i & 31;
        float4 v = ((const float4*)Wo)[i];
        WOt[(4 * jq + 0) * DOUT + o] = v.x; WOt[(4 * jq + 1) * DOUT + o] = v.y;
        WOt[(4 * jq + 2) * DOUT + o] = v.z; WOt[(4 * jq + 3) * DOUT + o] = v.w;
    }
    for (int i = tid; i < DOUT; i += 128) WOt[128 * DOUT + i] = 0.f;

    const float bil = bi2[ln], bih = bi2[64 + ln];
    const float bhl = bh2[ln], bhh = bh2[64 + ln];
    const bool  oth = (ln < DOUT);
    const float bov = oth ? bo[ln] : 0.f;
    unsigned long long p0 = 0ULL, p1 = 0ULL;
    float acc = 0.f;
    if (!first) {
        ulonglong2 st = state[s]; p0 = st.x; p1 = st.y;
        if (oth) acc = accst[s * DOUT + ln];
    }

    const float* Drow = D2 + (size_t)s * Tc * HID;
    float dl[8], dh[8];
    #pragma unroll
    for (int p = 0; p < 8; ++p) {
        int ti = p < Tc ? p : Tc - 1;
        dl[p] = Drow[ti * HID + ln];
        dh[p] = Drow[ti * HID + 64 + ln];
    }
    __syncthreads();

    for (int tt = 0; tt < Tc; tt += 8) {
        #pragma unroll
        for (int u = 0; u < 8; ++u) {
            int t = tt + u;
            if (t >= Tc) break;                       // wave-uniform
            float Al = dl[u], Ah = dh[u];
            int tp = (t + 8 < Tc) ? t + 8 : Tc - 1;
            dl[u] = Drow[tp * HID + ln];
            dh[u] = Drow[tp * HID + 64 + ln];

            float Bl = 0.f, Bh = 0.f;
            sparse4p(WT2, p0, 0,  ln2, Bl, Bh);
            sparse4p(WT2, p1, 64, ln2, Bl, Bh);

            float hl = ((Al + bil) + Bl) + bhl;       // reference add order
            float hh = ((Ah + bih) + Bh) + bhh;
            p0 = __ballot(hl >= 1.0f);
            p1 = __ballot(hh >= 1.0f);

            if (oth) {                                 // fused s2@Wo^T + bo
                float d = 0.f;
                unsigned long long mm = p0;
                while (mm) {
                    int j0 = (int)__builtin_ctzll(mm);       mm &= mm - 1;
                    int j1 = mm ? (int)__builtin_ctzll(mm) : 128; mm &= mm - 1;
                    int j2 = mm ? (int)__builtin_ctzll(mm) : 128; mm &= mm - 1;
                    int j3 = mm ? (int)__builtin_ctzll(mm) : 128; mm &= mm - 1;
                    float w0 = WOt[j0 * DOUT + ln], w1 = WOt[j1 * DOUT + ln];
                    float w2 = WOt[j2 * DOUT + ln], w3 = WOt[j3 * DOUT + ln];
                    d += w0; d += w1; d += w2; d += w3;
                }
                mm = p1;
                while (mm) {
                    int j0 = 64 + (int)__builtin_ctzll(mm);       mm &= mm - 1;
                    int j1 = mm ? 64 + (int)__builtin_ctzll(mm) : 128; mm &= mm - 1;
                    int j2 = mm ? 64 + (int)__builtin_ctzll(mm) : 128; mm &= mm - 1;
                    int j3 = mm ? 64 + (int)__builtin_ctzll(mm) : 128; mm &= mm - 1;
                    float w0 = WOt[j0 * DOUT + ln], w1 = WOt[j1 * DOUT + ln];
                    float w2 = WOt[j2 * DOUT + ln], w3 = WOt[j3 * DOUT + ln];
                    d += w0; d += w1; d += w2; d += w3;
                }
                acc += d;                              // (acc + dot) ...
                acc += bov;                            //  ... + bo
            }
        }
    }
    if (ln == 0) { ulonglong2 st; st.x = p0; st.y = p1; state[s] = st; }
    if (oth) {
        if (last) out[s * DOUT + ln] = acc / (float)T_STEPS;
        else      accst[s * DOUT + ln] = acc;
    }
}

// ---------------------------------------------------------------------------
extern "C" void kernel_launch(void* const* d_in, const int* in_sizes, int n_in,
                              void* d_out, int out_size, void* d_ws, size_t ws_size,
                              hipStream_t stream) {
    const float* x   = (const float*)d_in[0];
    const float* Wi1 = (const float*)d_in[1];
    const float* bi1 = (const float*)d_in[2];
    const float* Wh1 = (const float*)d_in[3];
    const float* bh1 = (const float*)d_in[4];
    const float* Wi2 = (const float*)d_in[5];
    const float* bi2 = (const float*)d_in[6];
    const float* Wh2 = (const float*)d_in[7];
    const float* bh2 = (const float*)d_in[8];
    const float* Wo  = (const float*)d_in[9];
    const float* bo  = (const float*)d_in[10];
    float* out = (float*)d_out;

    // ws: [masks1 8.19M][state 16K][accst 40K][D / D2 shared chunk buffer]
    const size_t mb = (size_t)NS * T_STEPS * sizeof(ulonglong2);
    ulonglong2* masks1 = (ulonglong2*)d_ws;
    ulonglong2* state  = (ulonglong2*)((char*)d_ws + mb);
    const size_t state_bytes = (size_t)2 * NS * sizeof(ulonglong2);
    float* accst = (float*)((char*)d_ws + mb + state_bytes);
    const size_t acc_bytes = (size_t)NS * DOUT * sizeof(float);
    float* Dbuf = (float*)((char*)d_ws + mb + state_bytes + acc_bytes);

    const size_t base = mb + state_bytes + acc_bytes;
    size_t avail = ws_size > base ? ws_size - base : 0;
    const size_t bytes_per_t = (size_t)NS * HID * sizeof(float);  // 256 KB
    long tcmax = (long)(avail / bytes_per_t);
    static const int divs[] = {1000, 500, 250, 200, 125, 100, 50, 40, 25, 20, 10, 8, 5, 4, 2, 1};
    int Tc = 1;
    for (int i = 0; i < 16; ++i) if (divs[i] <= tcmax) { Tc = divs[i]; break; }

    const int lds0 = (128 * XPAD + HID * HID) * (int)sizeof(float);
    const int ldsP = (129 * PSTR) * (int)sizeof(float);
    const int lds2 = (129 * PSTR + 129 * DOUT) * (int)sizeof(float);
    hipFuncSetAttribute((const void*)srnn_dense,
                        hipFuncAttributeMaxDynamicSharedMemorySize, lds0);
    hipFuncSetAttribute((const void*)srnn_recur1,
                        hipFuncAttributeMaxDynamicSharedMemorySize, ldsP);
    hipFuncSetAttribute((const void*)srnn_spmm,
                        hipFuncAttributeMaxDynamicSharedMemorySize, ldsP);
    hipFuncSetAttribute((const void*)srnn_recur2,
                        hipFuncAttributeMaxDynamicSharedMemorySize, lds2);

    // Phase A: layer-1 (dense GEMM chunk -> serial recurrence chunk)
    for (int t0 = 0; t0 < T_STEPS; t0 += Tc) {
        srnn_dense<<<4 * Tc, 512, lds0, stream>>>(x, Wi1, Dbuf, t0, Tc);
        srnn_recur1<<<NS / 2, 128, ldsP, stream>>>(Dbuf, Wh1, bi1, bh1,
                                                   masks1, state, t0, Tc, t0 == 0);
    }
    // Phase B: layer-2 (parallel spmm chunk -> serial recurrence + output)
    for (int t0 = 0; t0 < T_STEPS; t0 += Tc) {
        dim3 g2((Tc + 4 * SPMM_R - 1) / (4 * SPMM_R), NS);
        srnn_spmm<<<g2, 256, ldsP, stream>>>(masks1, Wi2, Dbuf, t0, Tc);
        srnn_recur2<<<NS / 2, 128, lds2, stream>>>(Dbuf, Wh2, bi2, bh2, Wo, bo,
                                                   state + NS, accst, out,
                                                   t0, Tc, t0 == 0,
                                                   t0 + Tc >= T_STEPS);
    }
}